// Round 1
// baseline (1200.096 us; speedup 1.0000x reference)
//
#include <hip/hip_runtime.h>
#include <math.h>

#define G 8192
#define D 1024
#define E 64
#define CAP 160
#define SLAB (E*CAP)                      // 10240 floats per token per tensor
#define OFF_COMB ((size_t)G*SLAB)         // 83886080
#define OFF_LOSS ((size_t)2*(size_t)G*SLAB)
#define OFF_M1 (OFF_LOSS+1)
#define OFF_M2 (OFF_M1+64)

// workspace element offsets (4B elements)
#define W_E1 0
#define W_E2 8192
#define W_R1 16384
#define W_R2 24576
#define W_G1 32768
#define W_G2 40960
#define W_H1 49152
#define W_H2 (49152+2048)
#define W_B1 (49152+4096)
#define W_B2 (49152+6144)
#define W_C1K (49152+8192)
#define W_SP  (49152+8192+64)             // 256 blocks * 64 floats

// ---------------- Kernel 1: GEMM + softmax + top2 ----------------
// grid 256 blocks x 256 thr. Wave = 64 lanes (lane <-> expert), 8 tokens/wave.
__global__ __launch_bounds__(256) void k_gating(const float* __restrict__ x,
                                                const float* __restrict__ w,
                                                int* __restrict__ wsi,
                                                float* __restrict__ wsf) {
  const int lane = threadIdx.x & 63;
  const int wid  = __builtin_amdgcn_readfirstlane(threadIdx.x >> 6);
  const int n0   = blockIdx.x * 32 + wid * 8;

  double acc[8] = {0,0,0,0,0,0,0,0};
  for (int kc = 0; kc < D; kc += 32) {
    double wd[32];
#pragma unroll
    for (int j = 0; j < 32; ++j) wd[j] = (double)w[(size_t)(kc + j) * E + lane];
#pragma unroll
    for (int t = 0; t < 8; ++t) {
      const float* xr = x + (size_t)(n0 + t) * D + kc;   // wave-uniform base -> scalar loads
      double a = acc[t];
#pragma unroll
      for (int j = 0; j < 32; ++j) a = fma((double)xr[j], wd[j], a);
      acc[t] = a;
    }
  }

  __shared__ float sp[256];
  float ps = 0.f;   // per-lane (expert) softmax-prob partial sum over this wave's 8 tokens

  for (int t = 0; t < 8; ++t) {
    float v = (float)acc[t];
    // top-1 (stable: lowest index on ties, matches jax.lax.top_k)
    float m = v; int mi = lane;
    for (int off = 32; off > 0; off >>= 1) {
      float ov = __shfl_xor(m, off, 64);
      int   oi = __shfl_xor(mi, off, 64);
      if (ov > m || (ov == m && oi < mi)) { m = ov; mi = oi; }
    }
    // top-2
    float v2 = (lane == mi) ? -__builtin_inff() : v;
    float m2 = v2; int mi2 = lane;
    for (int off = 32; off > 0; off >>= 1) {
      float ov = __shfl_xor(m2, off, 64);
      int   oi = __shfl_xor(mi2, off, 64);
      if (ov > m2 || (ov == m2 && oi < mi2)) { m2 = ov; mi2 = oi; }
    }
    float ex = expf(v - m);
    float den = ex;
    for (int off = 32; off > 0; off >>= 1) den += __shfl_xor(den, off, 64);
    ps += ex / den;

    float g1 = 1.0f / den;            // exp(0)/den
    float g2 = expf(m2 - m) / den;
    float s  = g1 + g2 + 1e-9f;
    float ga = g1 / s, gb = g2 / s;
    if (lane == 0) {
      int n = n0 + t;
      wsi[W_E1 + n] = mi;
      wsi[W_E2 + n] = mi2;
      wsf[W_G1 + n] = ga;
      wsf[W_G2 + n] = gb;
    }
  }
  sp[threadIdx.x] = ps;
  __syncthreads();
  if (threadIdx.x < 64) {
    wsf[W_SP + blockIdx.x * 64 + threadIdx.x] =
      sp[threadIdx.x] + sp[64 + threadIdx.x] + sp[128 + threadIdx.x] + sp[192 + threadIdx.x];
  }
}

// ---------------- Kernel 2: per-chunk ranks + histograms ----------------
// grid 32 blocks x 256 thr; chunk = 256 tokens.
__global__ __launch_bounds__(256) void k_rank(int* __restrict__ wsi) {
  __shared__ int hw1[4][64], hw2[4][64];
  const int t = threadIdx.x, b = blockIdx.x;
  const int lane = t & 63, w = t >> 6;
  if (t < 64) { for (int i = 0; i < 4; ++i) { hw1[i][t] = 0; hw2[i][t] = 0; } }
  __syncthreads();
  const int n = b * 256 + t;
  const int a  = wsi[W_E1 + n];
  const int e2 = wsi[W_E2 + n];
  int c1 = 0, c2 = 0;
  for (int j = 0; j < 64; ++j) {
    int ja = __shfl(a, j, 64);
    int jb = __shfl(e2, j, 64);
    if (j < lane) { c1 += (ja == a); c2 += (jb == e2); }
  }
  atomicAdd(&hw1[w][a], 1);
  atomicAdd(&hw2[w][e2], 1);
  __syncthreads();
  for (int ww = 0; ww < w; ++ww) { c1 += hw1[ww][a]; c2 += hw2[ww][e2]; }
  wsi[W_R1 + n] = c1;
  wsi[W_R2 + n] = c2;
  if (t < 64)
    wsi[W_H1 + b*64 + t] = hw1[0][t] + hw1[1][t] + hw1[2][t] + hw1[3][t];
  else if (t < 128) {
    int e = t - 64;
    wsi[W_H2 + b*64 + e] = hw2[0][e] + hw2[1][e] + hw2[2][e] + hw2[3][e];
  }
}

// ---------------- Kernel 3: cross-chunk prefix + counts + loss ----------------
// single block, 64 threads (thread = expert)
__global__ __launch_bounds__(64) void k_scan(int* __restrict__ wsi,
                                             const float* __restrict__ wsf,
                                             float* __restrict__ out) {
  const int e = threadIdx.x;
  int run1 = 0, run2 = 0;
  for (int c = 0; c < 32; ++c) {
    wsi[W_B1 + c*64 + e] = run1; run1 += wsi[W_H1 + c*64 + e];
    wsi[W_B2 + c*64 + e] = run2; run2 += wsi[W_H2 + c*64 + e];
  }
  int c1k = min(run1, CAP);
  wsi[W_C1K + e] = c1k;
  int m2c = min(run2, max(0, CAP - c1k));
  out[OFF_M1 + e] = (float)c1k;
  out[OFF_M2 + e] = (float)m2c;
  // loss = mean_e( (sumprob/8192) * (count1/8192) ) * 64^2
  float s = 0.f;
  for (int b = 0; b < 256; ++b) s += wsf[W_SP + b*64 + e];
  float term = (s * (1.0f/8192.f)) * ((float)run1 * (1.0f/8192.f));
  for (int off = 32; off > 0; off >>= 1) term += __shfl_xor(term, off, 64);
  if (e == 0) out[OFF_LOSS] = (term * (1.0f/64.f)) * 4096.0f;
}

// ---------------- Kernel 4: fill dispatch + combine ----------------
// one block per token; zero-fill 2 x 10240 floats, inject <=2 nonzeros inline.
__global__ __launch_bounds__(256) void k_fill(const int* __restrict__ wsi,
                                              const float* __restrict__ wsf,
                                              float* __restrict__ out) {
  const int n = blockIdx.x;
  const int t = threadIdx.x;
  const int e1 = __builtin_amdgcn_readfirstlane(wsi[W_E1 + n]);
  const int e2 = __builtin_amdgcn_readfirstlane(wsi[W_E2 + n]);
  const int c = n >> 8;
  const int p1 = wsi[W_B1 + c*64 + e1] + wsi[W_R1 + n];
  const int p2 = wsi[W_B2 + c*64 + e2] + wsi[W_R2 + n] + wsi[W_C1K + e2];
  const float g1 = wsf[W_G1 + n];
  const float g2 = wsf[W_G2 + n];
  // combine entry exists iff position < CAP and the gate value is nonzero
  // (dispatch = (combine != 0), so g2 underflow-to-0 must kill dispatch too)
  const int tgt1 = (p1 < CAP) ? (e1 * CAP + p1) : -100;
  const int tgt2 = (p2 < CAP && g2 != 0.0f) ? (e2 * CAP + p2) : -100;

  float4* __restrict__ dp = (float4*)out + (size_t)n * (SLAB/4);
  float4* __restrict__ cp = (float4*)(out + OFF_COMB) + (size_t)n * (SLAB/4);
#pragma unroll
  for (int i = 0; i < 10; ++i) {
    const int idx = i * 256 + t;
    const int f = idx * 4;
    float4 dv, cv;
    dv.x = (f     == tgt1 || f     == tgt2) ? 1.f : 0.f;
    dv.y = (f + 1 == tgt1 || f + 1 == tgt2) ? 1.f : 0.f;
    dv.z = (f + 2 == tgt1 || f + 2 == tgt2) ? 1.f : 0.f;
    dv.w = (f + 3 == tgt1 || f + 3 == tgt2) ? 1.f : 0.f;
    cv.x = (f     == tgt1) ? g1 : ((f     == tgt2) ? g2 : 0.f);
    cv.y = (f + 1 == tgt1) ? g1 : ((f + 1 == tgt2) ? g2 : 0.f);
    cv.z = (f + 2 == tgt1) ? g1 : ((f + 2 == tgt2) ? g2 : 0.f);
    cv.w = (f + 3 == tgt1) ? g1 : ((f + 3 == tgt2) ? g2 : 0.f);
    dp[idx] = dv;
    cp[idx] = cv;
  }
}

extern "C" void kernel_launch(void* const* d_in, const int* in_sizes, int n_in,
                              void* d_out, int out_size, void* d_ws, size_t ws_size,
                              hipStream_t stream) {
  const float* x = (const float*)d_in[0];
  const float* w = (const float*)d_in[1];
  float* out = (float*)d_out;
  int*   wsi = (int*)d_ws;
  float* wsf = (float*)d_ws;

  k_gating<<<256, 256, 0, stream>>>(x, w, wsi, wsf);
  k_rank  <<<32, 256, 0, stream>>>(wsi);
  k_scan  <<<1, 64, 0, stream>>>(wsi, wsf, out);
  k_fill  <<<8192, 256, 0, stream>>>(wsi, wsf, out);
}

// Round 2
// 740.039 us; speedup vs baseline: 1.6217x; 1.6217x over previous
//
#include <hip/hip_runtime.h>
#include <math.h>

#define G 8192
#define D 1024
#define E 64
#define CAP 160
#define SLAB (E*CAP)                      // 10240 floats per token per tensor
#define OFF_COMB ((size_t)G*SLAB)         // 83886080
#define OFF_LOSS ((size_t)2*(size_t)G*SLAB)
#define OFF_M1 (OFF_LOSS+1)
#define OFF_M2 (OFF_M1+64)

// workspace element offsets (4B elements)
#define W_E1 0
#define W_E2 8192
#define W_R1 16384
#define W_R2 24576
#define W_G1 32768
#define W_G2 40960
#define W_H1 49152
#define W_H2 (49152+2048)
#define W_B1 (49152+4096)
#define W_B2 (49152+6144)
#define W_C1K (49152+8192)
#define W_SP  (49152+8192+64)             // 512 blocks * 64 floats

// ---------------- Kernel 1: GEMM + softmax + top2 (fp32) ----------------
// grid 512 blocks x 256 thr. Wave = 64 lanes (lane <-> expert), 4 tokens/wave.
// x staged in LDS (read back as same-address float4 broadcast), w column in regs.
__global__ __launch_bounds__(256) void k_gating(const float* __restrict__ x,
                                                const float* __restrict__ w,
                                                int* __restrict__ wsi,
                                                float* __restrict__ wsf) {
  const int lane = threadIdx.x & 63;
  const int wid  = threadIdx.x >> 6;
  const int nblk = blockIdx.x * 16;      // 16 tokens per block
  const int n0   = nblk + wid * 4;       // 4 tokens per wave

  __shared__ float xs[16][64];           // 4 KB chunk of x
  float acc[4] = {0.f, 0.f, 0.f, 0.f};

  const int stok = threadIdx.x >> 4;           // 0..15 (staging token)
  const int sk   = (threadIdx.x & 15) * 4;     // 0..60 (staging k offset)
  const float* xsrc = x + (size_t)(nblk + stok) * D + sk;

  for (int kc = 0; kc < D; kc += 64) {
    *(float4*)&xs[stok][sk] = *(const float4*)(xsrc + kc);
    float wr[64];
#pragma unroll
    for (int j = 0; j < 64; ++j) wr[j] = w[(size_t)(kc + j) * E + lane];
    __syncthreads();
#pragma unroll
    for (int t = 0; t < 4; ++t) {
      const int tok = wid * 4 + t;
      float a = acc[t];
#pragma unroll
      for (int j4 = 0; j4 < 16; ++j4) {
        const float4 xv = *(const float4*)&xs[tok][j4 * 4];   // broadcast b128
        a = fmaf(xv.x, wr[j4*4+0], a);
        a = fmaf(xv.y, wr[j4*4+1], a);
        a = fmaf(xv.z, wr[j4*4+2], a);
        a = fmaf(xv.w, wr[j4*4+3], a);
      }
      acc[t] = a;
    }
    __syncthreads();
  }

  __shared__ float sp[256];
  float ps = 0.f;   // per-lane (expert) softmax-prob partial sum over this wave's tokens

  for (int t = 0; t < 4; ++t) {
    float v = acc[t];
    // top-1 (stable: lowest index on ties, matches jax.lax.top_k)
    float m = v; int mi = lane;
    for (int off = 32; off > 0; off >>= 1) {
      float ov = __shfl_xor(m, off, 64);
      int   oi = __shfl_xor(mi, off, 64);
      if (ov > m || (ov == m && oi < mi)) { m = ov; mi = oi; }
    }
    // top-2
    float v2 = (lane == mi) ? -__builtin_inff() : v;
    float m2 = v2; int mi2 = lane;
    for (int off = 32; off > 0; off >>= 1) {
      float ov = __shfl_xor(m2, off, 64);
      int   oi = __shfl_xor(mi2, off, 64);
      if (ov > m2 || (ov == m2 && oi < mi2)) { m2 = ov; mi2 = oi; }
    }
    float ex = expf(v - m);
    float den = ex;
    for (int off = 32; off > 0; off >>= 1) den += __shfl_xor(den, off, 64);
    ps += ex / den;

    float g1 = 1.0f / den;            // exp(0)/den
    float g2 = expf(m2 - m) / den;
    float s  = g1 + g2 + 1e-9f;
    float ga = g1 / s, gb = g2 / s;
    if (lane == 0) {
      int n = n0 + t;
      wsi[W_E1 + n] = mi;
      wsi[W_E2 + n] = mi2;
      wsf[W_G1 + n] = ga;
      wsf[W_G2 + n] = gb;
    }
  }
  sp[threadIdx.x] = ps;
  __syncthreads();
  if (threadIdx.x < 64) {
    wsf[W_SP + blockIdx.x * 64 + threadIdx.x] =
      sp[threadIdx.x] + sp[64 + threadIdx.x] + sp[128 + threadIdx.x] + sp[192 + threadIdx.x];
  }
}

// ---------------- Kernel 2: per-chunk ranks + histograms ----------------
// grid 32 blocks x 256 thr; chunk = 256 tokens.
__global__ __launch_bounds__(256) void k_rank(int* __restrict__ wsi) {
  __shared__ int hw1[4][64], hw2[4][64];
  const int t = threadIdx.x, b = blockIdx.x;
  const int lane = t & 63, w = t >> 6;
  if (t < 64) { for (int i = 0; i < 4; ++i) { hw1[i][t] = 0; hw2[i][t] = 0; } }
  __syncthreads();
  const int n = b * 256 + t;
  const int a  = wsi[W_E1 + n];
  const int e2 = wsi[W_E2 + n];
  int c1 = 0, c2 = 0;
  for (int j = 0; j < 64; ++j) {
    int ja = __shfl(a, j, 64);
    int jb = __shfl(e2, j, 64);
    if (j < lane) { c1 += (ja == a); c2 += (jb == e2); }
  }
  atomicAdd(&hw1[w][a], 1);
  atomicAdd(&hw2[w][e2], 1);
  __syncthreads();
  for (int ww = 0; ww < w; ++ww) { c1 += hw1[ww][a]; c2 += hw2[ww][e2]; }
  wsi[W_R1 + n] = c1;
  wsi[W_R2 + n] = c2;
  if (t < 64)
    wsi[W_H1 + b*64 + t] = hw1[0][t] + hw1[1][t] + hw1[2][t] + hw1[3][t];
  else if (t < 128) {
    int e = t - 64;
    wsi[W_H2 + b*64 + e] = hw2[0][e] + hw2[1][e] + hw2[2][e] + hw2[3][e];
  }
}

// ---------------- Kernel 3: cross-chunk prefix + counts + loss ----------------
// single block, 64 threads (thread = expert)
__global__ __launch_bounds__(64) void k_scan(int* __restrict__ wsi,
                                             const float* __restrict__ wsf,
                                             float* __restrict__ out) {
  const int e = threadIdx.x;
  int run1 = 0, run2 = 0;
  for (int c = 0; c < 32; ++c) {
    wsi[W_B1 + c*64 + e] = run1; run1 += wsi[W_H1 + c*64 + e];
    wsi[W_B2 + c*64 + e] = run2; run2 += wsi[W_H2 + c*64 + e];
  }
  int c1k = min(run1, CAP);
  wsi[W_C1K + e] = c1k;
  int m2c = min(run2, max(0, CAP - c1k));
  out[OFF_M1 + e] = (float)c1k;
  out[OFF_M2 + e] = (float)m2c;
  // loss = mean_e( (sumprob/8192) * (count1/8192) ) * 64^2
  float s = 0.f;
  for (int b = 0; b < 512; ++b) s += wsf[W_SP + b*64 + e];
  float term = (s * (1.0f/8192.f)) * ((float)run1 * (1.0f/8192.f));
  for (int off = 32; off > 0; off >>= 1) term += __shfl_xor(term, off, 64);
  if (e == 0) out[OFF_LOSS] = (term * (1.0f/64.f)) * 4096.0f;
}

// ---------------- Kernel 4: fill dispatch + combine ----------------
// one block per token; zero-fill 2 x 10240 floats, inject <=2 nonzeros inline.
__global__ __launch_bounds__(256) void k_fill(const int* __restrict__ wsi,
                                              const float* __restrict__ wsf,
                                              float* __restrict__ out) {
  const int n = blockIdx.x;
  const int t = threadIdx.x;
  const int e1 = __builtin_amdgcn_readfirstlane(wsi[W_E1 + n]);
  const int e2 = __builtin_amdgcn_readfirstlane(wsi[W_E2 + n]);
  const int c = n >> 8;
  const int p1 = wsi[W_B1 + c*64 + e1] + wsi[W_R1 + n];
  const int p2 = wsi[W_B2 + c*64 + e2] + wsi[W_R2 + n] + wsi[W_C1K + e2];
  const float g1 = wsf[W_G1 + n];
  const float g2 = wsf[W_G2 + n];
  // combine entry exists iff position < CAP and the gate value is nonzero
  // (dispatch = (combine != 0), so g2 underflow-to-0 must kill dispatch too)
  const int tgt1 = (p1 < CAP) ? (e1 * CAP + p1) : -100;
  const int tgt2 = (p2 < CAP && g2 != 0.0f) ? (e2 * CAP + p2) : -100;

  float4* __restrict__ dp = (float4*)out + (size_t)n * (SLAB/4);
  float4* __restrict__ cp = (float4*)(out + OFF_COMB) + (size_t)n * (SLAB/4);
#pragma unroll
  for (int i = 0; i < 10; ++i) {
    const int idx = i * 256 + t;
    const int f = idx * 4;
    float4 dv, cv;
    dv.x = (f     == tgt1 || f     == tgt2) ? 1.f : 0.f;
    dv.y = (f + 1 == tgt1 || f + 1 == tgt2) ? 1.f : 0.f;
    dv.z = (f + 2 == tgt1 || f + 2 == tgt2) ? 1.f : 0.f;
    dv.w = (f + 3 == tgt1 || f + 3 == tgt2) ? 1.f : 0.f;
    cv.x = (f     == tgt1) ? g1 : ((f     == tgt2) ? g2 : 0.f);
    cv.y = (f + 1 == tgt1) ? g1 : ((f + 1 == tgt2) ? g2 : 0.f);
    cv.z = (f + 2 == tgt1) ? g1 : ((f + 2 == tgt2) ? g2 : 0.f);
    cv.w = (f + 3 == tgt1) ? g1 : ((f + 3 == tgt2) ? g2 : 0.f);
    dp[idx] = dv;
    cp[idx] = cv;
  }
}

extern "C" void kernel_launch(void* const* d_in, const int* in_sizes, int n_in,
                              void* d_out, int out_size, void* d_ws, size_t ws_size,
                              hipStream_t stream) {
  const float* x = (const float*)d_in[0];
  const float* w = (const float*)d_in[1];
  float* out = (float*)d_out;
  int*   wsi = (int*)d_ws;
  float* wsf = (float*)d_ws;

  k_gating<<<512, 256, 0, stream>>>(x, w, wsi, wsf);
  k_rank  <<<32, 256, 0, stream>>>(wsi);
  k_scan  <<<1, 64, 0, stream>>>(wsi, wsf, out);
  k_fill  <<<8192, 256, 0, stream>>>(wsi, wsf, out);
}